// Round 6
// baseline (151.068 us; speedup 1.0000x reference)
//
#include <hip/hip_runtime.h>
#include <stdint.h>

#define D_K 512
#define C_CLS 85742
#define N_TILES 672            // 670 real + 2 pad (grid 2*672=1344 = 8*168)
#define N_PART (N_TILES * 2)

using bf16x8 = __attribute__((ext_vector_type(8))) short;
using f32x4  = __attribute__((ext_vector_type(4))) float;

// v_cvt_pk_bf16_f32: dst = {lo: bf16(a), hi: bf16(b)}, RNE. No builtin on
// gfx950 (m240) -> inline asm, non-volatile so the scheduler can move it.
__device__ __forceinline__ unsigned int cvtpk(float a, float b) {
  unsigned int r;
  asm("v_cvt_pk_bf16_f32 %0, %1, %2" : "=v"(r) : "v"(a), "v"(b));
  return r;
}
__device__ __forceinline__ unsigned short f2bf(float f) {
  unsigned int u = __builtin_bit_cast(unsigned int, f);
  u += 0x7FFFu + ((u >> 16) & 1u);          // round-to-nearest-even
  return (unsigned short)(u >> 16);
}
__device__ __forceinline__ float bf2f(unsigned short h) {
  return __builtin_bit_cast(float, ((unsigned int)h) << 16);
}
__device__ __forceinline__ float sq8(const float4& a, const float4& b) {
  return a.x*a.x + a.y*a.y + a.z*a.z + a.w*a.w +
         b.x*b.x + b.y*b.y + b.z*b.z + b.w*b.w;
}

// ---------------- Pass A: normalize x -> bf16 xn, save ||x|| ----------------
__global__ __launch_bounds__(256) void k_xnorm(const float* __restrict__ X,
                                               unsigned short* __restrict__ XN,
                                               float* __restrict__ FN) {
  int row  = blockIdx.x * 4 + (threadIdx.x >> 6);
  int lane = threadIdx.x & 63;
  const float4* px = (const float4*)(X + (size_t)row * D_K + lane * 8);
  float4 u = px[0], v = px[1];
  float nsq = sq8(u, v);
#pragma unroll
  for (int m = 1; m <= 32; m <<= 1) nsq += __shfl_xor(nsq, m);
  float nrm = sqrtf(nsq);
  float inv = 1.0f / fmaxf(nrm, 1e-12f);
  uint4 o;
  o.x = cvtpk(u.x*inv, u.y*inv); o.y = cvtpk(u.z*inv, u.w*inv);
  o.z = cvtpk(v.x*inv, v.y*inv); o.w = cvtpk(v.z*inv, v.w*inv);
  *(uint4*)(XN + (size_t)row * D_K + lane * 8) = o;
  if (lane == 0) FN[row] = nrm;
}

// ---- Pass C: 256x128 bf16 MFMA GEMM (512 thr, 8 waves 4m x 2n, wave-tile
// ---- 64x64, BK=32, dbuf LDS, one barrier/K-step, static buffer indices).
// ---- Each W element converted 2x/dispatch (vs 4x at BM=128): B fp32 regs ->
// ---- cvt_pk -> bf16 LDS + fused ||w||^2. A = xn bf16 via global_load_lds.
// ---- Epilogue: per-(row,64col) (max,sumexp) partials of z=clamp(cos)*||x||.
__global__ __launch_bounds__(512, 2) void k_gemm_lse(const float* __restrict__ W,
                                                     const unsigned short* __restrict__ XN,
                                                     const float* __restrict__ FN,
                                                     float2* __restrict__ PART) {
  __shared__ alignas(16) unsigned short As[2][8192];   // [buf][256 rows x 32 cols]
  __shared__ alignas(16) unsigned short Bs[2][4096];   // [buf][128 rows x 32 cols]
  __shared__ float nsqS[128];
  __shared__ float fnS[256];

  int bid = blockIdx.x;
  // bijective XCD chunking: 1344 = 8*168; both m-blocks of an n-tile on one XCD
  int wg    = (bid & 7) * 168 + (bid >> 3);
  int ntile = wg >> 1, mtile = wg & 1;
  int m0 = mtile * 256, n0 = ntile * 128;

  int t    = threadIdx.x;
  int lane = t & 63, wid = t >> 6;          // 8 waves
  int wm = wid >> 1, wn = wid & 1;          // 4 x 2 wave grid
  int s = lane & 15, g = lane >> 4;

  // B staging: thread t owns row t>>2 (4 thr/row), f32 cols (t&3)*8..+7.
  // OOB rows clamp (uniform, branch-free); epilogue masks them.
  int rB = t >> 2;
  int gr = n0 + rB; if (gr > C_CLS - 1) gr = C_CLS - 1;
  const float* pB = W + (size_t)gr * D_K + (t & 3) * 8;

  // A staging via global_load_lds(16B): wave wid, inst j covers rows
  // wid*32 + j*16 + (lane>>2), col (lane&3)*8; linear LDS dest.
  const unsigned short* gA0 = XN + (size_t)(m0 + wid * 32 + (lane >> 2)) * D_K + (lane & 3) * 8;
  f32x4 acc[4][4] = {};
  float nsq = 0.f;
  float4 ra0, ra1;

#define GLDS(srcp, dstp) __builtin_amdgcn_global_load_lds( \
    (const __attribute__((address_space(1))) unsigned int*)(srcp), \
    (__attribute__((address_space(3))) unsigned int*)(dstp), 16, 0, 0)

#define STAGE_A(b, kk) do { \
    GLDS(gA0 + (size_t)(kk) * 32,            &As[b][wid * 1024]); \
    GLDS(gA0 + 16 * D_K + (size_t)(kk) * 32, &As[b][wid * 1024 + 512]); \
  } while (0)

#define PREF_B(kk) do { \
    const float* q_ = pB + (size_t)(kk) * 32; \
    ra0 = *(const float4*)q_; ra1 = *(const float4*)(q_ + 4); \
  } while (0)

#define CONV_B(b) do { \
    nsq += sq8(ra0, ra1); \
    uint4 u_; \
    u_.x = cvtpk(ra0.x, ra0.y); u_.y = cvtpk(ra0.z, ra0.w); \
    u_.z = cvtpk(ra1.x, ra1.y); u_.w = cvtpk(ra1.z, ra1.w); \
    *(uint4*)(&Bs[b][rB * 32 + (t & 3) * 8]) = u_; \
  } while (0)

#define FRAGS_MFMA(b) do { \
    bf16x8 af[4], bfr[4]; \
    _Pragma("unroll") for (int mf = 0; mf < 4; ++mf) \
      af[mf] = *(const bf16x8*)(&As[b][(wm * 64 + mf * 16 + s) * 32 + g * 8]); \
    _Pragma("unroll") for (int nf = 0; nf < 4; ++nf) \
      bfr[nf] = *(const bf16x8*)(&Bs[b][(wn * 64 + nf * 16 + s) * 32 + g * 8]); \
    _Pragma("unroll") for (int mf = 0; mf < 4; ++mf) \
      _Pragma("unroll") for (int nf = 0; nf < 4; ++nf) \
        acc[mf][nf] = __builtin_amdgcn_mfma_f32_16x16x32_bf16(af[mf], bfr[nf], acc[mf][nf], 0, 0, 0); \
  } while (0)

  // ---- prologue: tile 0 into buf0 ----
  STAGE_A(0, 0);
  PREF_B(0);
  if (t < 256) fnS[t] = FN[m0 + t];
  CONV_B(0);                    // waits B(0) regs; glds(0) older -> also done
  __syncthreads();              // buf0 fully visible

  // ---- main loop: 16 K-steps, ONE barrier each, static buffer indices ----
  for (int kt = 0; kt < 14; kt += 2) {
    STAGE_A(1, kt + 1);
    PREF_B(kt + 1);
    FRAGS_MFMA(0);
    CONV_B(1);
    __syncthreads();
    STAGE_A(0, kt + 2);
    PREF_B(kt + 2);
    FRAGS_MFMA(1);
    CONV_B(0);
    __syncthreads();
  }
  STAGE_A(1, 15);
  PREF_B(15);
  FRAGS_MFMA(0);                // kt = 14
  CONV_B(1);
  __syncthreads();
  FRAGS_MFMA(1);                // kt = 15

  // finish per-row ||w||^2: combine the 4 col-chunk owners (t^1, t^2)
  nsq += __shfl_xor(nsq, 1); nsq += __shfl_xor(nsq, 2);
  if ((t & 3) == 0) nsqS[rB] = nsq;
  __syncthreads();

  float rinv[4]; int cvalid[4];
#pragma unroll
  for (int nf = 0; nf < 4; ++nf) {
    int cl = wn * 64 + nf * 16 + s;
    cvalid[nf] = (n0 + cl) < C_CLS;
    rinv[nf] = 1.0f / fmaxf(sqrtf(nsqS[cl]), 1e-12f);
  }
  const float NEG_INF = -__builtin_inff();
#pragma unroll
  for (int mf = 0; mf < 4; ++mf) {
#pragma unroll
    for (int q = 0; q < 4; ++q) {
      int rl = wm * 64 + mf * 16 + g * 4 + q;     // D row = (lane>>4)*4+reg
      float fr = fnS[rl];
      float z[4]; float mx = NEG_INF;
#pragma unroll
      for (int nf = 0; nf < 4; ++nf) {
        float cc = acc[mf][nf][q] * rinv[nf];
        cc = fminf(fmaxf(cc, -1.0f), 1.0f);
        z[nf] = cvalid[nf] ? cc * fr : NEG_INF;
        mx = fmaxf(mx, z[nf]);
      }
#pragma unroll
      for (int d = 1; d <= 8; d <<= 1) mx = fmaxf(mx, __shfl_xor(mx, d));
      float se = 0.f;
#pragma unroll
      for (int nf = 0; nf < 4; ++nf) se += __expf(z[nf] - mx);  // exp(-inf)=0
#pragma unroll
      for (int d = 1; d <= 8; d <<= 1) se += __shfl_xor(se, d);
      if (s == mf * 4 + q)
        PART[(size_t)(m0 + rl) * N_PART + (ntile * 2 + wn)] = make_float2(mx, se);
    }
  }
}

// ------- Pass D: per-row target logit (unmodified + margin-modified) --------
__global__ __launch_bounds__(64) void k_target(const float* __restrict__ W,
                                               const unsigned short* __restrict__ XN,
                                               const float* __restrict__ FN,
                                               const int* __restrict__ LBL,
                                               float2* __restrict__ ZT) {
  int row = blockIdx.x;
  int lane = threadIdx.x;
  int lab = LBL[row];
  const float* pw = W + (size_t)lab * D_K + lane * 8;
  const unsigned short* px = XN + (size_t)row * D_K + lane * 8;
  float dot = 0.f, nsq = 0.f;
#pragma unroll
  for (int j = 0; j < 8; ++j) {
    float w = pw[j];
    nsq += w * w;
    dot += bf2f(px[j]) * bf2f(f2bf(w));   // match GEMM numerics (bf16 operands)
  }
#pragma unroll
  for (int m = 1; m <= 32; m <<= 1) { dot += __shfl_xor(dot, m); nsq += __shfl_xor(nsq, m); }
  if (lane == 0) {
    const float LAMB = 1000.0f / 1.12f;   // iter=1 -> max(5, 1000/1.12)
    float rinv = 1.0f / fmaxf(sqrtf(nsq), 1e-12f);
    float c = fminf(fmaxf(dot * rinv, -1.0f), 1.0f);
    float c2 = c * c;
    float cm = 8.0f * c2 * c2 - 8.0f * c2 + 1.0f;   // cos(4θ)
    float th = acosf(c);
    float kf = floorf(4.0f * th / 3.14159265f);
    float phi = ((((int)kf) & 1) ? -cm : cm) - 2.0f * kf;
    float fr = FN[row];
    float zu = fr * c;
    float zm = fr * (c + (phi - c) / (1.0f + LAMB));
    ZT[row] = make_float2(zu, zm);
  }
}

// ------- Pass E1: combine 1344 partials per row -> per-row CE loss ----------
__global__ __launch_bounds__(256) void k_lse(const float2* __restrict__ PART,
                                             const float2* __restrict__ ZT,
                                             float* __restrict__ LOSSI) {
  int row = blockIdx.x;
  int t = threadIdx.x;
  const float NEG_INF = -__builtin_inff();
  float m = NEG_INF, ss = 0.f;
  for (int p = t; p < N_PART; p += 256) {
    float2 ps = PART[(size_t)row * N_PART + p];
    if (ps.y > 0.f) {            // NaN/0 (pad or all-invalid tiles) -> skip
      if (ps.x > m) { ss = ss * __expf(m - ps.x) + ps.y; m = ps.x; }
      else          { ss += ps.y * __expf(ps.x - m); }
    }
  }
  __shared__ float sm[256], sv[256];
  sm[t] = m; sv[t] = ss;
  __syncthreads();
  for (int o = 128; o > 0; o >>= 1) {
    if (t < o) {
      float m1 = sm[t], s1 = sv[t];
      float m2 = sm[t + o], s2 = sv[t + o];
      float mm = fmaxf(m1, m2);
      float e1 = (m1 > NEG_INF) ? s1 * __expf(m1 - mm) : 0.f;
      float e2 = (m2 > NEG_INF) ? s2 * __expf(m2 - mm) : 0.f;
      sm[t] = mm; sv[t] = e1 + e2;
    }
    __syncthreads();
  }
  if (t == 0) {
    float M = sm[0], S = sv[0];
    float2 zt = ZT[row];
    // swap the target's unmodified exp term for the margin-modified one
    S += __expf(zt.y - M) - __expf(zt.x - M);
    LOSSI[row] = M + logf(S) - zt.y;
  }
}

// ------- Pass E2: mean over 512 rows -> scalar loss -------------------------
__global__ __launch_bounds__(256) void k_mean(const float* __restrict__ LOSSI,
                                              float* __restrict__ OUT) {
  int t = threadIdx.x;
  float s_ = LOSSI[t] + LOSSI[t + 256];
#pragma unroll
  for (int m = 1; m <= 32; m <<= 1) s_ += __shfl_xor(s_, m);
  __shared__ float wsum[4];
  if ((t & 63) == 0) wsum[t >> 6] = s_;
  __syncthreads();
  if (t == 0) OUT[0] = (wsum[0] + wsum[1] + wsum[2] + wsum[3]) * (1.0f / 512.0f);
}

extern "C" void kernel_launch(void* const* d_in, const int* in_sizes, int n_in,
                              void* d_out, int out_size, void* d_ws, size_t ws_size,
                              hipStream_t stream) {
  const float* X   = (const float*)d_in[0];   // [512,512] f32
  const float* W   = (const float*)d_in[1];   // [85742,512] f32
  const int*   LBL = (const int*)d_in[2];     // [512] i32
  float* OUT = (float*)d_out;

  char* ws = (char*)d_ws;
  unsigned short* XN = (unsigned short*)ws;            // 512*512*2       = 524288
  float*  FN    = (float*)(ws + 524288);               // 512*4           = 2048
  float2* ZT    = (float2*)(ws + 526336);              // 512*8           = 4096
  float*  LOSSI = (float*)(ws + 530432);               // 512*4           = 2048
  float2* PART  = (float2*)(ws + 532480);              // 512*1344*8      = 5505024

  k_xnorm  <<<dim3(128),  dim3(256), 0, stream>>>(X, XN, FN);
  k_gemm_lse<<<dim3(1344), dim3(512), 0, stream>>>(W, XN, FN, PART);
  k_target <<<dim3(512),  dim3(64),  0, stream>>>(W, XN, FN, LBL, ZT);
  k_lse    <<<dim3(512),  dim3(256), 0, stream>>>(PART, ZT, LOSSI);
  k_mean   <<<dim3(1),    dim3(256), 0, stream>>>(LOSSI, OUT);
}

// Round 7
// 108.971 us; speedup vs baseline: 1.3863x; 1.3863x over previous
//
#include <hip/hip_runtime.h>
#include <stdint.h>

#define D_K 512
#define C_CLS 85742
#define N_TILES 670            // ceil(85742/128)
#define N_PART (N_TILES * 2)

using bf16x8 = __attribute__((ext_vector_type(8))) short;
using f32x4  = __attribute__((ext_vector_type(4))) float;

// v_cvt_pk_bf16_f32: dst = {lo: bf16(a), hi: bf16(b)}, RNE. No builtin on
// gfx950 (m240) -> inline asm, non-volatile so the scheduler can move it.
__device__ __forceinline__ unsigned int cvtpk(float a, float b) {
  unsigned int r;
  asm("v_cvt_pk_bf16_f32 %0, %1, %2" : "=v"(r) : "v"(a), "v"(b));
  return r;
}
__device__ __forceinline__ unsigned short f2bf(float f) {
  unsigned int u = __builtin_bit_cast(unsigned int, f);
  u += 0x7FFFu + ((u >> 16) & 1u);          // round-to-nearest-even
  return (unsigned short)(u >> 16);
}
__device__ __forceinline__ float bf2f(unsigned short h) {
  return __builtin_bit_cast(float, ((unsigned int)h) << 16);
}
__device__ __forceinline__ float sq8(const float4& a, const float4& b) {
  return a.x*a.x + a.y*a.y + a.z*a.z + a.w*a.w +
         b.x*b.x + b.y*b.y + b.z*b.z + b.w*b.w;
}

// ---------------- Pass A: normalize x -> bf16 xn, save ||x|| ----------------
__global__ __launch_bounds__(256) void k_xnorm(const float* __restrict__ X,
                                               unsigned short* __restrict__ XN,
                                               float* __restrict__ FN) {
  int row  = blockIdx.x * 4 + (threadIdx.x >> 6);
  int lane = threadIdx.x & 63;
  const float4* px = (const float4*)(X + (size_t)row * D_K + lane * 8);
  float4 u = px[0], v = px[1];
  float nsq = sq8(u, v);
#pragma unroll
  for (int m = 1; m <= 32; m <<= 1) nsq += __shfl_xor(nsq, m);
  float nrm = sqrtf(nsq);
  float inv = 1.0f / fmaxf(nrm, 1e-12f);
  uint4 o;
  o.x = cvtpk(u.x*inv, u.y*inv); o.y = cvtpk(u.z*inv, u.w*inv);
  o.z = cvtpk(v.x*inv, v.y*inv); o.w = cvtpk(v.z*inv, v.w*inv);
  *(uint4*)(XN + (size_t)row * D_K + lane * 8) = o;
  if (lane == 0) FN[row] = nrm;
}

// ---- Pass C: 128x128 bf16 MFMA GEMM. 512 thr / 8 waves (4m x 2n), wave-tile
// ---- 32x64 -> acc[2][4] = 32 regs/wave => ~105 unified regs => 4 waves/SIMD
// ---- (2 blocks/CU, 16 waves). BK=32, dbuf LDS. Counted-vmcnt barrier: per
// ---- K-step outstanding at barrier = [glds(kt+1), B(kt+2)x2] -> vmcnt(2)
// ---- drains glds only; the 2-deep B-prefetch survives the barrier (~2
// ---- compute phases of L3-latency coverage). B fp32 regs -> cvt_pk -> LDS
// ---- with fused ||w||^2. Epilogue: per-(row,64col) (max,sumexp) partials.
__global__ __launch_bounds__(512) void k_gemm_lse(const float* __restrict__ W,
                                                  const unsigned short* __restrict__ XN,
                                                  const float* __restrict__ FN,
                                                  float2* __restrict__ PART) {
  __shared__ alignas(16) unsigned short As[2][4096];   // [buf][128 rows x 32 cols]
  __shared__ alignas(16) unsigned short Bs[2][4096];
  __shared__ float nsqS[128];
  __shared__ float fnS[128];

  int bid = blockIdx.x;
  // bijective XCD chunking: 2680 = 8*335; 4 m-blocks of an n-tile stay on one XCD
  int wg    = (bid & 7) * 335 + (bid >> 3);
  int ntile = wg >> 2, mtile = wg & 3;
  int m0 = mtile * 128, n0 = ntile * 128;

  int t    = threadIdx.x;
  int lane = t & 63, wid = t >> 6;          // 8 waves
  int wm = wid >> 1, wn = wid & 1;          // 4m x 2n wave grid, tile 32x64
  int s = lane & 15, g = lane >> 4;

  // B staging: thread t owns row rB=t>>2, f32 cols (t&3)*8..+7 (8 f32/thread).
  // OOB rows clamp (uniform, branch-free); epilogue masks them.
  int rB = t >> 2;
  int gr = n0 + rB; if (gr > C_CLS - 1) gr = C_CLS - 1;
  const float* pB = W + (size_t)gr * D_K + (t & 3) * 8;

  // A staging via global_load_lds(16B), 1 instr/wave: wave wid stages rows
  // [wid*16, wid*16+16), lane -> row wid*16+(lane>>2), col (lane&3)*8.
  const unsigned short* gA0 = XN + (size_t)(m0 + wid * 16 + (lane >> 2)) * D_K + (lane & 3) * 8;

  f32x4 acc[2][4] = {};
  float nsq = 0.f;
  float4 xa0, xa1;   // B reg set X (even K-steps)
  float4 ya0, ya1;   // B reg set Y (odd K-steps)

#define GLDS(srcp, dstp) __builtin_amdgcn_global_load_lds( \
    (const __attribute__((address_space(1))) unsigned int*)(srcp), \
    (__attribute__((address_space(3))) unsigned int*)(dstp), 16, 0, 0)

#define STAGE_A(b, kk) GLDS(gA0 + (size_t)(kk) * 32, &As[b][wid * 512])

#define PREF_X(kk) do { const float* q_ = pB + (size_t)(kk) * 32; \
    xa0 = *(const float4*)q_; xa1 = *(const float4*)(q_ + 4); } while (0)
#define PREF_Y(kk) do { const float* q_ = pB + (size_t)(kk) * 32; \
    ya0 = *(const float4*)q_; ya1 = *(const float4*)(q_ + 4); } while (0)

#define CONV_X(b) do { nsq += sq8(xa0, xa1); \
    uint4 u_; u_.x = cvtpk(xa0.x, xa0.y); u_.y = cvtpk(xa0.z, xa0.w); \
    u_.z = cvtpk(xa1.x, xa1.y); u_.w = cvtpk(xa1.z, xa1.w); \
    *(uint4*)(&Bs[b][rB * 32 + (t & 3) * 8]) = u_; } while (0)
#define CONV_Y(b) do { nsq += sq8(ya0, ya1); \
    uint4 u_; u_.x = cvtpk(ya0.x, ya0.y); u_.y = cvtpk(ya0.z, ya0.w); \
    u_.z = cvtpk(ya1.x, ya1.y); u_.w = cvtpk(ya1.z, ya1.w); \
    *(uint4*)(&Bs[b][rB * 32 + (t & 3) * 8]) = u_; } while (0)

#define FRAGS_MFMA(b) do { \
    bf16x8 af[2], bfr[4]; \
    _Pragma("unroll") for (int mf = 0; mf < 2; ++mf) \
      af[mf] = *(const bf16x8*)(&As[b][(wm * 32 + mf * 16 + s) * 32 + g * 8]); \
    _Pragma("unroll") for (int nf = 0; nf < 4; ++nf) \
      bfr[nf] = *(const bf16x8*)(&Bs[b][(wn * 64 + nf * 16 + s) * 32 + g * 8]); \
    _Pragma("unroll") for (int mf = 0; mf < 2; ++mf) \
      _Pragma("unroll") for (int nf = 0; nf < 4; ++nf) \
        acc[mf][nf] = __builtin_amdgcn_mfma_f32_16x16x32_bf16(af[mf], bfr[nf], acc[mf][nf], 0, 0, 0); \
  } while (0)

  // counted barrier: drains the glds (oldest of the 3 outstanding VMEM ops),
  // leaves the 2 B-prefetch loads in flight across the barrier.
#define BARC() do { \
    asm volatile("s_waitcnt vmcnt(2) lgkmcnt(0)" ::: "memory"); \
    __builtin_amdgcn_s_barrier(); } while (0)
#define BAR0() do { \
    asm volatile("s_waitcnt vmcnt(0) lgkmcnt(0)" ::: "memory"); \
    __builtin_amdgcn_s_barrier(); } while (0)

  // ---- prologue: buf0 <- tile 0; B(1) in flight ----
  STAGE_A(0, 0);
  PREF_X(0);
  PREF_Y(1);
  if (t < 128) fnS[t] = FN[m0 + t];
  CONV_X(0);      // compiler wait drains X (and the older glds0) ; Y stays
  BARC();         // queue [Ya,Yb] -> no-op wait; publishes buf0

  // ---- main loop: step kt computes buf cur, stages kt+1, prefetches kt+2 ----
  for (int kt = 0; kt < 14; kt += 2) {
    // even kt: consume set Y (kt+1), refill set X (kt+2)
    STAGE_A(1, kt + 1);
    PREF_X(kt + 2);
    FRAGS_MFMA(0);
    CONV_Y(1);
    BARC();       // queue [glds(kt+1), X(kt+2)x2] -> drain glds only
    // odd kt+1: consume set X (kt+2), refill set Y (kt+3)
    STAGE_A(0, kt + 2);
    PREF_Y(kt + 3);
    FRAGS_MFMA(1);
    CONV_X(0);
    BARC();
  }
  // kt = 14
  STAGE_A(1, 15);
  FRAGS_MFMA(0);
  CONV_Y(1);      // B(15), loaded at kt=13
  BAR0();         // only glds(15) outstanding -> full drain
  // kt = 15
  FRAGS_MFMA(1);

  // finish per-row ||w||^2: combine the 4 col-chunk owners (t^1, t^2)
  nsq += __shfl_xor(nsq, 1); nsq += __shfl_xor(nsq, 2);
  if ((t & 3) == 0) nsqS[rB] = nsq;
  __syncthreads();

  float rinv[4]; int cvalid[4];
#pragma unroll
  for (int nf = 0; nf < 4; ++nf) {
    int cl = wn * 64 + nf * 16 + s;
    cvalid[nf] = (n0 + cl) < C_CLS;
    rinv[nf] = 1.0f / fmaxf(sqrtf(nsqS[cl]), 1e-12f);
  }
  const float NEG_INF = -__builtin_inff();
#pragma unroll
  for (int mf = 0; mf < 2; ++mf) {
#pragma unroll
    for (int q = 0; q < 4; ++q) {
      int rl = wm * 32 + mf * 16 + g * 4 + q;     // D row = (lane>>4)*4+reg
      float fr = fnS[rl];
      float z[4]; float mx = NEG_INF;
#pragma unroll
      for (int nf = 0; nf < 4; ++nf) {
        float cc = acc[mf][nf][q] * rinv[nf];
        cc = fminf(fmaxf(cc, -1.0f), 1.0f);
        z[nf] = cvalid[nf] ? cc * fr : NEG_INF;
        mx = fmaxf(mx, z[nf]);
      }
#pragma unroll
      for (int d = 1; d <= 8; d <<= 1) mx = fmaxf(mx, __shfl_xor(mx, d));
      float se = 0.f;
#pragma unroll
      for (int nf = 0; nf < 4; ++nf) se += __expf(z[nf] - mx);  // exp(-inf)=0
#pragma unroll
      for (int d = 1; d <= 8; d <<= 1) se += __shfl_xor(se, d);
      if (s == mf * 4 + q)
        PART[(size_t)(m0 + rl) * N_PART + (ntile * 2 + wn)] = make_float2(mx, se);
    }
  }
}

// ------- Pass D: per-row target logit (unmodified + margin-modified) --------
__global__ __launch_bounds__(64) void k_target(const float* __restrict__ W,
                                               const unsigned short* __restrict__ XN,
                                               const float* __restrict__ FN,
                                               const int* __restrict__ LBL,
                                               float2* __restrict__ ZT) {
  int row = blockIdx.x;
  int lane = threadIdx.x;
  int lab = LBL[row];
  const float* pw = W + (size_t)lab * D_K + lane * 8;
  const unsigned short* px = XN + (size_t)row * D_K + lane * 8;
  float dot = 0.f, nsq = 0.f;
#pragma unroll
  for (int j = 0; j < 8; ++j) {
    float w = pw[j];
    nsq += w * w;
    dot += bf2f(px[j]) * bf2f(f2bf(w));   // match GEMM numerics (bf16 operands)
  }
#pragma unroll
  for (int m = 1; m <= 32; m <<= 1) { dot += __shfl_xor(dot, m); nsq += __shfl_xor(nsq, m); }
  if (lane == 0) {
    const float LAMB = 1000.0f / 1.12f;   // iter=1 -> max(5, 1000/1.12)
    float rinv = 1.0f / fmaxf(sqrtf(nsq), 1e-12f);
    float c = fminf(fmaxf(dot * rinv, -1.0f), 1.0f);
    float c2 = c * c;
    float cm = 8.0f * c2 * c2 - 8.0f * c2 + 1.0f;   // cos(4θ)
    float th = acosf(c);
    float kf = floorf(4.0f * th / 3.14159265f);
    float phi = ((((int)kf) & 1) ? -cm : cm) - 2.0f * kf;
    float fr = FN[row];
    float zu = fr * c;
    float zm = fr * (c + (phi - c) / (1.0f + LAMB));
    ZT[row] = make_float2(zu, zm);
  }
}

// ------- Pass E1: combine 1340 partials per row -> per-row CE loss ----------
__global__ __launch_bounds__(256) void k_lse(const float2* __restrict__ PART,
                                             const float2* __restrict__ ZT,
                                             float* __restrict__ LOSSI) {
  int row = blockIdx.x;
  int t = threadIdx.x;
  const float NEG_INF = -__builtin_inff();
  float m = NEG_INF, ss = 0.f;
  for (int p = t; p < N_PART; p += 256) {
    float2 ps = PART[(size_t)row * N_PART + p];
    if (ps.y > 0.f) {
      if (ps.x > m) { ss = ss * __expf(m - ps.x) + ps.y; m = ps.x; }
      else          { ss += ps.y * __expf(ps.x - m); }
    }
  }
  __shared__ float sm[256], sv[256];
  sm[t] = m; sv[t] = ss;
  __syncthreads();
  for (int o = 128; o > 0; o >>= 1) {
    if (t < o) {
      float m1 = sm[t], s1 = sv[t];
      float m2 = sm[t + o], s2 = sv[t + o];
      float mm = fmaxf(m1, m2);
      float e1 = (m1 > NEG_INF) ? s1 * __expf(m1 - mm) : 0.f;
      float e2 = (m2 > NEG_INF) ? s2 * __expf(m2 - mm) : 0.f;
      sm[t] = mm; sv[t] = e1 + e2;
    }
    __syncthreads();
  }
  if (t == 0) {
    float M = sm[0], S = sv[0];
    float2 zt = ZT[row];
    // swap the target's unmodified exp term for the margin-modified one
    S += __expf(zt.y - M) - __expf(zt.x - M);
    LOSSI[row] = M + logf(S) - zt.y;
  }
}

// ------- Pass E2: mean over 512 rows -> scalar loss -------------------------
__global__ __launch_bounds__(256) void k_mean(const float* __restrict__ LOSSI,
                                              float* __restrict__ OUT) {
  int t = threadIdx.x;
  float s_ = LOSSI[t] + LOSSI[t + 256];
#pragma unroll
  for (int m = 1; m <= 32; m <<= 1) s_ += __shfl_xor(s_, m);
  __shared__ float wsum[4];
  if ((t & 63) == 0) wsum[t >> 6] = s_;
  __syncthreads();
  if (t == 0) OUT[0] = (wsum[0] + wsum[1] + wsum[2] + wsum[3]) * (1.0f / 512.0f);
}

extern "C" void kernel_launch(void* const* d_in, const int* in_sizes, int n_in,
                              void* d_out, int out_size, void* d_ws, size_t ws_size,
                              hipStream_t stream) {
  const float* X   = (const float*)d_in[0];   // [512,512] f32
  const float* W   = (const float*)d_in[1];   // [85742,512] f32
  const int*   LBL = (const int*)d_in[2];     // [512] i32
  float* OUT = (float*)d_out;

  char* ws = (char*)d_ws;
  unsigned short* XN = (unsigned short*)ws;            // 512*512*2       = 524288
  float*  FN    = (float*)(ws + 524288);               // 512*4           = 2048
  float2* ZT    = (float2*)(ws + 526336);               // 512*8           = 4096
  float*  LOSSI = (float*)(ws + 530432);               // 512*4           = 2048
  float2* PART  = (float2*)(ws + 532480);              // 512*1340*8      = 5488640

  k_xnorm  <<<dim3(128),  dim3(256), 0, stream>>>(X, XN, FN);
  k_gemm_lse<<<dim3(2680), dim3(512), 0, stream>>>(W, XN, FN, PART);
  k_target <<<dim3(512),  dim3(64),  0, stream>>>(W, XN, FN, LBL, ZT);
  k_lse    <<<dim3(512),  dim3(256), 0, stream>>>(PART, ZT, LOSSI);
  k_mean   <<<dim3(1),    dim3(256), 0, stream>>>(LOSSI, OUT);
}